// Round 6
// baseline (2053.054 us; speedup 1.0000x reference)
//
#include <hip/hip_runtime.h>
#include <hip/hip_fp16.h>

#define NN 8192
#define NCOLS 101      // y + 100 probes
#define CPW 112        // Vp stored columns (101 used, 112 allocated)
#define BN 128         // compute columns (padded; Pb cols 101..127 are zero)
#define BM 128
#define KSPL 8
#define KCH (NN / KSPL)    // 1024 fp8 elems (=bytes) per split
#define NSTEP (KCH / 128)  // 8 steps of BK=128
#define PITER 30
#define PVLD 104           // pvp row stride (101 rounded up)

typedef __attribute__((ext_vector_type(4))) float f32x4;

__device__ __forceinline__ void async_copy16(const void* g, void* l) {
  __builtin_amdgcn_global_load_lds(
      (const __attribute__((address_space(1))) unsigned int*)g,
      (__attribute__((address_space(3))) unsigned int*)l, 16, 0, 0);
}

__device__ __forceinline__ unsigned int pack_fp8x4(float x, float y, float z, float w) {
  unsigned int v = __builtin_amdgcn_cvt_pk_fp8_f32(x, y, 0, false);
  v = __builtin_amdgcn_cvt_pk_fp8_f32(z, w, v, true);
  return v;
}

// 256-thread (4-wave) block sum; valid on thread 0 only; leading barrier makes
// back-to-back calls safe.
__device__ __forceinline__ float block_sum(float v) {
  __shared__ float sw[4];
  __syncthreads();
  #pragma unroll
  for (int o = 32; o > 0; o >>= 1) v += __shfl_down(v, o);
  int w = threadIdx.x >> 6;
  if ((threadIdx.x & 63) == 0) sw[w] = v;
  __syncthreads();
  float r = 0.f;
  if (threadIdx.x < 4) r = sw[threadIdx.x];
  r += __shfl_down(r, 2);
  r += __shfl_down(r, 1);
  return r;
}

// 1024-thread (16-wave) block sum; valid on thread 0 only.
__device__ __forceinline__ float block_sum1024(float v) {
  __shared__ float sw[16];
  __syncthreads();
  #pragma unroll
  for (int o = 32; o > 0; o >>= 1) v += __shfl_down(v, o);
  int w = threadIdx.x >> 6;
  if ((threadIdx.x & 63) == 0) sw[w] = v;
  __syncthreads();
  float r = 0.f;
  if (threadIdx.x < 16) r = sw[threadIdx.x];
  r += __shfl_down(r, 8);
  r += __shfl_down(r, 4);
  r += __shfl_down(r, 2);
  r += __shfl_down(r, 1);
  return r;
}

// ---------------- GEMM: Vp[kz] = K-panel @ Phat (fp8 MFMA) + pv partials ----------------
// MEASUREMENT ROUND: identical to R5 except the staging+MFMA K-loop runs `reps` times
// (reps=16 on iteration 0, else 1). The gemm is idempotent — acc is re-zeroed per rep,
// only the final rep's acc reaches the epilogue, so output is bit-identical. asm
// keep-alives stop DCE of earlier reps (guide rule #17).
//   * (dur_us - 1915)/15 = true per-rep K-loop time (separates inner-loop cost from
//     dispatch mechanics).
//   * The 16x dispatch lands in rocprof top-5: FETCH_SIZE ~1 GB => Kbt re-streams from
//     HBM every pass; ~64-150 MB => Infinity Cache retains it. Plus real MfmaUtil/
//     bank-conflict/occupancy for the core loop.
__global__ __launch_bounds__(256, 2) void gemm_kernel(
    const unsigned char* __restrict__ Kbt,
    const unsigned char* __restrict__ Pb,
    const float* __restrict__ Pf,
    const float* __restrict__ SCit,
    __half* __restrict__ Vp,
    float* __restrict__ pvp,
    int reps) {
  __shared__ __align__(16) unsigned char smem[65536];
  unsigned char* sA = smem;          // [2][BM*128]
  unsigned char* sB = smem + 32768;  // [2][BN*128]
  float* sC = (float*)smem;          // [BM][113], post-loop overlay

  int bx = blockIdx.x;
  int kz = bx & 7;
  int rb = bx >> 3;
  int tid = threadIdx.x;
  int lane = tid & 63;
  int w = tid >> 6;
  int r0 = rb * BM;
  int k0 = kz * KCH;
  int lrow = lane >> 3;
  int gseg = (lane & 7) ^ lrow;
  int asrc = lrow * 128 + gseg * 16;
  int mm = lane & 15;
  int quad = lane >> 4;
  int q1 = quad >> 1, q0 = quad & 1;
  int wm = w >> 1, wn = w & 1;   // wave grid 2M x 2N, wave tile 64x64

  const unsigned char* Apanel = Kbt + ((size_t)bx << 17);

  int aBase[4], aXor[4], bBase[4], bXor[4];
  #pragma unroll
  for (int i = 0; i < 4; ++i) {
    int arow = wm * 64 + i * 16 + mm;
    aBase[i] = arow * 128 + (q0 << 3);
    aXor[i] = (arow & 7) << 4;
    int bcol = wn * 64 + i * 16 + mm;
    bBase[i] = bcol * 128 + (q0 << 3);
    bXor[i] = (bcol & 7) << 4;
  }

  f32x4 acc[4][4];

  auto stage = [&](int s, int buf) {
    int kk = k0 + s * 128;
    #pragma unroll
    for (int q = 0; q < 4; ++q) {  // wave w stages rows/cols w*32 + q*8 + lrow
      async_copy16(Apanel + (s << 14) + (w * 32 + q * 8) * 128 + asrc,
                   sA + buf * 16384 + (w * 32 + q * 8) * 128);
      async_copy16(Pb + (size_t)(w * 32 + q * 8 + lrow) * NN + kk + gseg * 16,
                   sB + buf * 16384 + (w * 32 + q * 8) * 128);
    }
  };

  for (int rep = 0; rep < reps; ++rep) {
    #pragma unroll
    for (int i = 0; i < 4; ++i)
      #pragma unroll
      for (int j = 0; j < 4; ++j) acc[i][j] = (f32x4){0.f, 0.f, 0.f, 0.f};

    stage(0, 0);
    __syncthreads();  // vmcnt(0): prologue tile landed

    #pragma unroll 2
    for (int s = 0; s < NSTEP; ++s) {
      int cur = s & 1;
      if (s + 1 < NSTEP) stage(s + 1, cur ^ 1);  // prefetch next tile
      const unsigned char* A = sA + cur * 16384;
      const unsigned char* B = sB + cur * 16384;
      #pragma unroll
      for (int kh = 0; kh < 4; ++kh) {
        int s16 = (kh * 2 + q1) << 4;
        long long aF[4], bF[4];
        #pragma unroll
        for (int i = 0; i < 4; ++i) {
          aF[i] = *(const long long*)(A + aBase[i] + (s16 ^ aXor[i]));
          bF[i] = *(const long long*)(B + bBase[i] + (s16 ^ bXor[i]));
        }
        #pragma unroll
        for (int i = 0; i < 4; ++i)
          #pragma unroll
          for (int j = 0; j < 4; ++j)
            acc[i][j] = __builtin_amdgcn_mfma_f32_16x16x32_fp8_fp8(aF[i], bF[j], acc[i][j], 0, 0, 0);
      }
      __syncthreads();  // lgkmcnt(0) WAR + vmcnt(0) RAW for the dbuf swap
    }
    if (rep != reps - 1) {  // keep earlier reps' MFMAs live (anti-DCE), then redo
      #pragma unroll
      for (int i = 0; i < 4; ++i)
        #pragma unroll
        for (int j = 0; j < 4; ++j)
          asm volatile("" : : "v"(acc[i][j]));
    }
  }
  // epilogue: transpose through LDS (C/D frag layout: col=lane&15, row=quad*4+r)
  #pragma unroll
  for (int i = 0; i < 4; ++i)
    #pragma unroll
    for (int j = 0; j < 4; ++j) {
      int ctile = wn * 64 + j * 16;
      if (ctile >= CPW) continue;
      #pragma unroll
      for (int r = 0; r < 4; ++r)
        sC[(wm * 64 + i * 16 + quad * 4 + r) * 113 + ctile + mm] = acc[i][j][r];
    }
  __syncthreads();
  const size_t SPL = (size_t)CPW * NN;
  __half* Vout = Vp + (size_t)kz * SPL;
  for (int idx = tid; idx < BM * CPW; idx += 256) {
    int col = idx >> 7;
    int row = idx & 127;
    if (col < NCOLS)
      Vout[(size_t)col * NN + r0 + row] = __float2half(sC[row * 113 + col] * SCit[col]);
  }
  // pv partial: wave g handles cols {g, g+4, ...}; lanes = rows (coalesced P reads)
  int rr = tid & 63;
  int g = tid >> 6;
  for (int j = 0; j < 26; ++j) {
    int c = g + j * 4;
    float prod = 0.f;
    if (c < NCOLS)
      prod = (sC[rr * 113 + c] * Pf[(size_t)c * NN + r0 + rr] +
              sC[(rr + 64) * 113 + c] * Pf[(size_t)c * NN + r0 + 64 + rr]) * SCit[c];
    #pragma unroll
    for (int o = 32; o > 0; o >>= 1) prod += __shfl_down(prod, o);
    if (rr == 0 && c < NCOLS) pvp[(size_t)bx * PVLD + c] = prod;
  }
}

// ---------------- fused update: ONE block per column, whole chain block-local ----------
__global__ __launch_bounds__(1024, 1) void update_kernel(
    const __half* __restrict__ Vp, float* __restrict__ P,
    float* __restrict__ R, float* __restrict__ X0,
    unsigned char* __restrict__ Pb, const float* __restrict__ pvp,
    float* __restrict__ SM, int it) {
  float* RS = SM;                // [31][128]
  float* AL = SM + 7808;         // [30][128]
  float* BE = SM + 11648;        // [30][128]
  float* PN = SM + 15488;        // [31][128]
  float* SC = SM + 19456;        // [31][128]
  __shared__ float sbc[2];

  int c = blockIdx.x;   // 0..100
  int t = threadIdx.x;  // 0..1023
  const size_t SPL = (size_t)CPW * NN;
  size_t base = (size_t)c * NN;

  // pv total for this column (512 gemm-block partials)
  float pvv = (t < 512) ? pvp[(size_t)t * PVLD + c] : 0.f;
  float pvtot = block_sum1024(pvv);
  float rs_old = RS[it * 128 + c];
  if (t == 0) sbc[0] = rs_old / pvtot;
  __syncthreads();
  float alpha = sbc[0];

  // R update (keep r in regs for the P phase); rn partial
  float4 rv[2];
  float rn = 0.f;
  #pragma unroll
  for (int j = 0; j < 2; ++j) {
    size_t off = base + j * 4096 + t * 4;
    float4 v = {0.f, 0.f, 0.f, 0.f};
    #pragma unroll
    for (int sp = 0; sp < KSPL; ++sp) {
      const __half2* ph = (const __half2*)(Vp + sp * SPL + off);
      float2 f01 = __half22float2(ph[0]);
      float2 f23 = __half22float2(ph[1]);
      v.x += f01.x; v.y += f01.y; v.z += f23.x; v.w += f23.y;
    }
    float4 r = *(float4*)(R + off);
    r.x -= alpha * v.x; r.y -= alpha * v.y;
    r.z -= alpha * v.z; r.w -= alpha * v.w;
    *(float4*)(R + off) = r;
    rv[j] = r;
    rn += r.x * r.x + r.y * r.y + r.z * r.z + r.w * r.w;
    if (c == 0) {
      size_t xo = j * 4096 + t * 4;
      float4 x = *(float4*)(X0 + xo);
      float4 p = *(const float4*)(P + off);
      x.x += alpha * p.x; x.y += alpha * p.y;
      x.z += alpha * p.z; x.w += alpha * p.w;
      *(float4*)(X0 + xo) = x;
    }
  }
  float rsn = block_sum1024(rn);
  if (t == 0) {
    float beta = rsn / rs_old;
    float pnn = rsn + beta * beta * PN[it * 128 + c];  // ||P_new||^2 (CG identity)
    float sc = exp2f(roundf(0.5f * log2f(pnn * (1.f / 8192.f))));
    AL[it * 128 + c] = alpha;
    BE[it * 128 + c] = beta;
    PN[(it + 1) * 128 + c] = pnn;
    SC[(it + 1) * 128 + c] = sc;
    RS[(it + 1) * 128 + c] = rsn;
    sbc[0] = beta;
    sbc[1] = 1.f / sc;
  }
  __syncthreads();
  if (it < PITER - 1) {
    float beta = sbc[0], inv = sbc[1];
    #pragma unroll
    for (int j = 0; j < 2; ++j) {
      size_t off = base + j * 4096 + t * 4;
      float4 p = *(float4*)(P + off);
      p.x = rv[j].x + beta * p.x; p.y = rv[j].y + beta * p.y;
      p.z = rv[j].z + beta * p.z; p.w = rv[j].w + beta * p.w;
      *(float4*)(P + off) = p;
      *(unsigned int*)(Pb + off) = pack_fp8x4(p.x * inv, p.y * inv, p.z * inv, p.w * inv);
    }
  }
}

// ---------------- fused init: cast K->Kbt panels + vec init + zero + rs0 --------------
__global__ void init_all(const float* __restrict__ K, const float* __restrict__ y,
                         const float* __restrict__ Z, unsigned char* __restrict__ Kbt,
                         unsigned char* __restrict__ Pb, float* __restrict__ P,
                         float* __restrict__ R, float* __restrict__ X0,
                         float* __restrict__ SM) {
  int b = blockIdx.x;
  int t = threadIdx.x;
  int gid = b * 256 + t;
  const int gsz = 512 * 256;
  // cast K -> tiled fp8 panels
  for (size_t u = gid; u < (size_t)NN * NN / 16; u += gsz) {
    size_t d = u * 16;
    int p = (int)(d >> 17);
    int rem = (int)(d & 131071);
    int s = rem >> 14;
    int row = (rem >> 7) & 127;
    int cb = rem & 127;
    int r = (p >> 3) * 128 + row;
    int c = (p & 7) * KCH + s * 128 + cb;
    const float* src = K + (size_t)r * NN + c;
    float4 f0 = *(const float4*)(src);
    float4 f1 = *(const float4*)(src + 4);
    float4 f2 = *(const float4*)(src + 8);
    float4 f3 = *(const float4*)(src + 12);
    uint4 o;
    o.x = pack_fp8x4(f0.x, f0.y, f0.z, f0.w);
    o.y = pack_fp8x4(f1.x, f1.y, f1.z, f1.w);
    o.z = pack_fp8x4(f2.x, f2.y, f2.z, f2.w);
    o.w = pack_fp8x4(f3.x, f3.y, f3.z, f3.w);
    *(uint4*)(Kbt + d) = o;
  }
  // P/R/Pb from y,Z
  for (int v = gid; v < NCOLS * NN; v += gsz) {
    int c = v >> 13;
    int i = v & 8191;
    float val = (c == 0) ? y[i] : Z[(size_t)i * 100 + (c - 1)];
    size_t off = (size_t)c * NN + i;
    P[off] = val;
    R[off] = val;
    Pb[off] = (unsigned char)(__builtin_amdgcn_cvt_pk_fp8_f32(val, 0.f, 0, false) & 0xFF);
  }
  // zero X0 and Pb padding cols 101..127
  for (int i = gid; i < 8192 + 27 * NN; i += gsz) {
    if (i < 8192) X0[i] = 0.f;
    else Pb[(size_t)NCOLS * NN + (i - 8192)] = 0;
  }
  // scalar seeds (block 511): RS/PN row 0, SC row 0
  if (b == 511) {
    float* RS = SM;
    float* PN = SM + 15488;
    float* SC = SM + 19456;
    float s = 0.f;
    for (int i = t; i < NN; i += 256) { float v = y[i]; s += v * v; }
    float tot = block_sum(s);
    if (t == 0) { RS[0] = tot; PN[0] = tot; }
    if (t >= 1 && t <= 100) { RS[t] = (float)NN; PN[t] = (float)NN; }
    if (t < 128) SC[t] = 1.f;
  }
}

// ---------------- SLQ: Sturm bisection + Gauss-weight recurrence, fp64 ----------------
__global__ __launch_bounds__(64, 1) void slq_kernel(
    const float* __restrict__ AL, const float* __restrict__ BE,
    float* __restrict__ QP) {
  __shared__ double sd[PITER], se[PITER];
  int lane = threadIdx.x;
  int c = blockIdx.x + 1;
  if (lane < PITER) {
    double a = (double)AL[lane * 128 + c];
    double dd = 1.0 / a;
    if (lane > 0) {
      double ap = (double)AL[(lane - 1) * 128 + c];
      double bp = (double)BE[(lane - 1) * 128 + c];
      dd += bp / ap;
    }
    sd[lane] = dd;
    double ee = 0.0;
    if (lane < PITER - 1) {
      double b = (double)BE[lane * 128 + c];
      ee = sqrt(b) / a;
    }
    se[lane] = ee;
  }
  __syncthreads();
  double d[PITER], e[PITER];
  #pragma unroll
  for (int i = 0; i < PITER; ++i) { d[i] = sd[i]; e[i] = se[i]; }

  float quadk = 0.f;
  if (lane < PITER) {
    double lo = 1e300, hi = -1e300;
    #pragma unroll
    for (int i = 0; i < PITER; ++i) {
      double r = e[i] + (i > 0 ? e[i - 1] : 0.0);
      lo = fmin(lo, d[i] - r);
      hi = fmax(hi, d[i] + r);
    }
    int k = lane;
    for (int it = 0; it < 48; ++it) {
      double mid = 0.5 * (lo + hi);
      int cnt = 0;
      double q = d[0] - mid;
      cnt += (q < 0.0);
      #pragma unroll
      for (int i = 1; i < PITER; ++i) {
        double aq = fabs(q);
        if (aq < 1e-30) q = (q < 0.0) ? -1e-30 : 1e-30;
        q = d[i] - mid - (e[i - 1] * e[i - 1]) / q;
        cnt += (q < 0.0);
      }
      if (cnt > k) hi = mid; else lo = mid;
    }
    double lam = 0.5 * (lo + hi);
    double e0 = fmax(e[0], 1e-150);
    double vprev = 1.0;
    double vcur = (lam - d[0]) / e0;
    double s = 1.0 + vcur * vcur;
    double scale2 = 1.0;
    #pragma unroll
    for (int i = 1; i < PITER - 1; ++i) {
      double ei = fmax(e[i], 1e-150);
      double vnext = ((lam - d[i]) * vcur - e[i - 1] * vprev) / ei;
      if (fabs(vnext) > 1e150) {
        vnext *= 1e-150; vcur *= 1e-150; s *= 1e-300; scale2 *= 1e-300;
      }
      vprev = vcur; vcur = vnext;
      s += vcur * vcur;
    }
    double w = scale2 / s;
    double lc = lam > 1e-12 ? lam : 1e-12;
    quadk = (float)(w * log(lc));
  }
  #pragma unroll
  for (int o = 32; o > 0; o >>= 1) quadk += __shfl_down(quadk, o);
  if (lane == 0) QP[blockIdx.x] = quadk;
}

// ---------------- final: ydot + combine ----------------
__global__ void final2_kernel(const float* __restrict__ y, const float* __restrict__ X0,
                              const float* __restrict__ QP, float* __restrict__ out) {
  int t = threadIdx.x;
  float s = 0.f;
  for (int i = t; i < NN; i += 256) s += y[i] * X0[i];
  float ydot = block_sum(s);
  __syncthreads();
  float q = (t < 100) ? QP[t] : 0.f;
  float qsum = block_sum(q);
  if (t == 0) {
    float logdet = (float)NN * (qsum * 0.01f);
    out[0] = -0.5f * ydot - 0.5f * logdet - (float)NN * 0.5f * 1.8378770664093454f;
  }
}

extern "C" void kernel_launch(void* const* d_in, const int* in_sizes, int n_in,
                              void* d_out, int out_size, void* d_ws, size_t ws_size,
                              hipStream_t stream) {
  const float* K = (const float*)d_in[0];
  const float* y = (const float*)d_in[1];
  const float* Z = (const float*)d_in[2];
  float* out = (float*)d_out;
  char* ws = (char*)d_ws;
  if (ws_size < 89796096ull) return;  // need ~85.6 MiB

  unsigned char* Kbt = (unsigned char*)(ws + 0ull);       // 67,108,864 (tiled panels)
  unsigned char* Pb = (unsigned char*)(ws + 67108864ull); //  1,048,576 (128 cols)
  float* P   = (float*)(ws + 68157440ull);                //  3,309,568 (101 cols)
  float* R   = (float*)(ws + 71467008ull);                //  3,309,568
  __half* Vp = (__half*)(ws + 74776576ull);               // 14,680,064 (8 splits x 112 cols, fp16)
  float* X0  = (float*)(ws + 89456640ull);                //     32,768
  float* PVP = (float*)(ws + 89489408ull);                //    212,992 (512 x 104)
  float* SM  = (float*)(ws + 89702400ull);                //     93,696 scalar block
  float* AL = SM + 7808;        // [30][128]
  float* BE = SM + 11648;       // [30][128]
  float* SC = SM + 19456;       // [31][128]
  float* QP = (float*)(ws + 74776576ull);  // 100 floats, reuses Vp after CG loop

  init_all<<<512, 256, 0, stream>>>(K, y, Z, Kbt, Pb, P, R, X0, SM);

  for (int it = 0; it < PITER; ++it) {
    // it==0: 16 internal K-loop reps (idempotent; diagnostic probe — see gemm comment)
    gemm_kernel<<<512, 256, 0, stream>>>(Kbt, Pb, P, SC + it * 128, Vp, PVP,
                                         it == 0 ? 16 : 1);
    update_kernel<<<NCOLS, 1024, 0, stream>>>(Vp, P, R, X0, Pb, PVP, SM, it);
  }
  slq_kernel<<<100, 64, 0, stream>>>(AL, BE, QP);
  final2_kernel<<<1, 256, 0, stream>>>(y, X0, QP, out);
}